// Round 2
// baseline (665.965 us; speedup 1.0000x reference)
//
#include <hip/hip_runtime.h>

#define NCLASS 1000
#define HALF 32                      // dims per dim-group (64 total, split 2 ways)
#define ACC_WORDS (NCLASS * HALF)    // 32000 floats per partial slot (128 KB)
#define WARMUP 1000
#define TPB 1024                     // 16 waves/CU (LDS caps us at 1 block/CU)
#define UNROLL 4                     // rows prefetched per thread per iteration

// ---------------------------------------------------------------------------
__global__ void bank_zero_kernel(float* __restrict__ p, int n) {
    int i = blockIdx.x * blockDim.x + threadIdx.x;
    if (i < n) p[i] = 0.0f;
}

// ---------------------------------------------------------------------------
// Per-block LDS-privatized segment sum over a contiguous row chunk.
// blockIdx.x = chunk*2 + dim_group. 1024 threads: 8 lanes per row (float4
// each), 128 rows per batch, UNROLL batches prefetched into registers before
// the LDS atomics (ILP to cover HBM latency). LDS word index XOR-swizzled by
// (label&31) to randomize ds_add_f32 banks.
__global__ __launch_bounds__(TPB, 4)
void bank_accum_kernel(const float* __restrict__ feat,
                       const int* __restrict__ label,
                       int n, int rows_per_chunk, int nchunk,
                       float* __restrict__ psums,   // partial slots OR [NCLASS][64] global acc
                       int* __restrict__ counts,
                       int atomic_mode)
{
    __shared__ float table[ACC_WORDS];   // 128 KB
    __shared__ int   hist[NCLASS];       // 4 KB (used by dim-group 0 only)

    const int tid   = threadIdx.x;
    const int g     = blockIdx.x & 1;    // dim group: 0 -> dims 0..31, 1 -> 32..63
    const int chunk = blockIdx.x >> 1;

    float4* t4 = reinterpret_cast<float4*>(table);
    for (int i = tid; i < ACC_WORDS / 4; i += TPB) t4[i] = make_float4(0.f, 0.f, 0.f, 0.f);
    if (g == 0)
        for (int i = tid; i < NCLASS; i += TPB) hist[i] = 0;
    __syncthreads();

    const int row0 = chunk * rows_per_chunk;
    const int row1 = min(n, row0 + rows_per_chunk);
    const int sub  = tid & 7;            // which float4 of the 32-dim half
    const int rloc = tid >> 3;           // 0..127: row within the 128-row batch
    const int dbase = g * HALF + sub * 4;
    const int RPI  = TPB / 8;            // 128 rows per batch
    const int w    = sub * 4;

    int r = row0 + rloc;
    // main loop: prefetch UNROLL rows' labels+features, then LDS-accumulate
    for (; r + (UNROLL - 1) * RPI < row1; r += UNROLL * RPI) {
        int    lab[UNROLL];
        float4 v[UNROLL];
        #pragma unroll
        for (int u = 0; u < UNROLL; ++u) {
            lab[u] = label[r + u * RPI];
            v[u]   = *reinterpret_cast<const float4*>(feat + (size_t)(r + u * RPI) * 64 + dbase);
        }
        #pragma unroll
        for (int u = 0; u < UNROLL; ++u) {
            const int swz  = lab[u] & 31;
            const int base = lab[u] * HALF;
            atomicAdd(&table[base + ((w + 0) ^ swz)], v[u].x);
            atomicAdd(&table[base + ((w + 1) ^ swz)], v[u].y);
            atomicAdd(&table[base + ((w + 2) ^ swz)], v[u].z);
            atomicAdd(&table[base + ((w + 3) ^ swz)], v[u].w);
            if (g == 0 && sub == 0) atomicAdd(&hist[lab[u]], 1);
        }
    }
    // tail
    for (; r < row1; r += RPI) {
        const int l = label[r];
        const float4 v = *reinterpret_cast<const float4*>(feat + (size_t)r * 64 + dbase);
        const int swz  = l & 31;
        const int base = l * HALF;
        atomicAdd(&table[base + ((w + 0) ^ swz)], v.x);
        atomicAdd(&table[base + ((w + 1) ^ swz)], v.y);
        atomicAdd(&table[base + ((w + 2) ^ swz)], v.z);
        atomicAdd(&table[base + ((w + 3) ^ swz)], v.w);
        if (g == 0 && sub == 0) atomicAdd(&hist[l], 1);
    }
    __syncthreads();

    if (!atomic_mode) {
        // exclusive partial slot: un-swizzle while flushing (scalar stores;
        // permutation stays within one 128B line so writes still coalesce)
        float* slot = psums + (size_t)(g * nchunk + chunk) * ACC_WORDS;
        for (int i = tid; i < ACC_WORDS; i += TPB) {
            const int c = i >> 5, dsw = i & 31;
            slot[(c << 5) | (dsw ^ (c & 31))] = table[i];
        }
    } else {
        // fallback: accumulate into d_out used as [NCLASS][64] sum buffer
        for (int i = tid; i < ACC_WORDS; i += TPB) {
            const int c = i >> 5, dsw = i & 31;
            const float v = table[i];
            if (v != 0.0f) atomicAdd(&psums[c * 64 + g * HALF + (dsw ^ (c & 31))], v);
        }
    }
    if (g == 0) {
        for (int i = tid; i < NCLASS; i += TPB)
            if (hist[i]) atomicAdd(&counts[i], hist[i]);
    }
}

// ---------------------------------------------------------------------------
// One wave (64 lanes) per class: reduce partials, mean, EMA logic.
__global__ void bank_finalize_kernel(const float* __restrict__ proto,
                                     const float* __restrict__ psums,
                                     const int* __restrict__ counts,
                                     const int* __restrict__ step_ptr,
                                     float* __restrict__ out,
                                     int nchunk, int atomic_mode)
{
    const int c = blockIdx.x * 4 + (threadIdx.x >> 6);   // 4 classes per 256-thr block
    const int d = threadIdx.x & 63;                      // dim = lane

    float s = 0.0f;
    if (!atomic_mode) {
        const int g = d >> 5, dd = d & 31;
        const float* base = psums + ((size_t)g * nchunk * NCLASS + c) * HALF + dd;
        #pragma unroll 4
        for (int k = 0; k < nchunk; ++k)
            s += base[(size_t)k * ACC_WORDS];
    } else {
        s = out[c * 64 + d];   // sums were atomically accumulated in-place
    }

    const int   cnt  = counts[c];
    const float mean = s / (float)(cnt > 0 ? cnt : 1);
    const float p    = proto[c * 64 + d];

    // zero_proto: all 64 dims of this class's prototype row are exactly 0
    const unsigned long long nzmask = __ballot(p != 0.0f);
    const bool use_new = (nzmask == 0ULL) || (step_ptr[0] <= WARMUP);

    const float lam = 0.9f;
    const float upd = use_new ? mean : (lam * p + (1.0f - lam) * mean);
    out[c * 64 + d] = (cnt > 0) ? upd : p;
}

// ---------------------------------------------------------------------------
extern "C" void kernel_launch(void* const* d_in, const int* in_sizes, int n_in,
                              void* d_out, int out_size, void* d_ws, size_t ws_size,
                              hipStream_t stream)
{
    const float* proto = (const float*)d_in[0];
    const float* feat  = (const float*)d_in[1];
    const int*   label = (const int*)d_in[2];
    const int*   step  = (const int*)d_in[3];
    float* out = (float*)d_out;
    const int n = in_sizes[2];

    int*   counts   = (int*)d_ws;                       // 4 KB
    float* partials = (float*)((char*)d_ws + 4096);     // 2*nchunk slots of 128 KB

    int nchunk = 128;
    while (nchunk > 1 &&
           (4096 + (size_t)2 * nchunk * ACC_WORDS * 4) > ws_size)
        nchunk >>= 1;
    const int atomic_mode =
        ((4096 + (size_t)2 * nchunk * ACC_WORDS * 4) > ws_size) ? 1 : 0;
    if (atomic_mode) nchunk = 128;   // ws too small: atomics into d_out instead

    bank_zero_kernel<<<(NCLASS + 255) / 256, 256, 0, stream>>>((float*)counts, NCLASS);
    if (atomic_mode)
        bank_zero_kernel<<<(NCLASS * 64 + 255) / 256, 256, 0, stream>>>(out, NCLASS * 64);

    const int rows_per = (n + nchunk - 1) / nchunk;
    bank_accum_kernel<<<2 * nchunk, TPB, 0, stream>>>(
        feat, label, n, rows_per, nchunk,
        atomic_mode ? out : partials, counts, atomic_mode);

    bank_finalize_kernel<<<NCLASS / 4, 256, 0, stream>>>(
        proto, atomic_mode ? out : partials, counts, step, out, nchunk, atomic_mode);
}

// Round 3
// 149.031 us; speedup vs baseline: 4.4686x; 4.4686x over previous
//
#include <hip/hip_runtime.h>

#define NCLASS 1000
#define D 64
#define WARMUP 1000
#define NBLK 512            // partition blocks for histogram / scatter
#define K1_TPB 256
#define K4_TPB 1024

// ---------------------------------------------------------------------------
// K1: per-block label histogram -> cnt_t[c * NBLK + b]   (transposed layout)
__global__ __launch_bounds__(K1_TPB)
void k1_hist(const int* __restrict__ label, int n, int rpb,
             int* __restrict__ cnt_t)
{
    __shared__ int hist[NCLASS];
    const int b = blockIdx.x, tid = threadIdx.x;
    for (int i = tid; i < NCLASS; i += K1_TPB) hist[i] = 0;
    __syncthreads();
    const int r0 = b * rpb, r1 = min(n, r0 + rpb);
    for (int r = r0 + tid; r < r1; r += K1_TPB)
        atomicAdd(&hist[label[r]], 1);
    __syncthreads();
    for (int i = tid; i < NCLASS; i += K1_TPB)
        cnt_t[i * NBLK + b] = hist[i];
}

// ---------------------------------------------------------------------------
// K2a: totals[c] = sum_b cnt_t[c][b]   (one wave per class)
__global__ __launch_bounds__(256)
void k2a_totals(const int* __restrict__ cnt_t, int* __restrict__ totals)
{
    const int c = blockIdx.x * 4 + (threadIdx.x >> 6);
    const int lane = threadIdx.x & 63;
    if (c >= NCLASS) return;
    int s = 0;
    for (int k = lane; k < NBLK; k += 64) s += cnt_t[c * NBLK + k];
    for (int off = 32; off; off >>= 1) s += __shfl_down(s, off);
    if (lane == 0) totals[c] = s;
}

// ---------------------------------------------------------------------------
// K2b: exclusive scan of totals -> base[c]   (single block)
__global__ __launch_bounds__(1024)
void k2b_scan(const int* __restrict__ totals, int* __restrict__ base)
{
    __shared__ int buf[1024];
    const int t = threadIdx.x;
    const int mine = (t < NCLASS) ? totals[t] : 0;
    buf[t] = mine;
    __syncthreads();
    for (int off = 1; off < 1024; off <<= 1) {
        const int v = (t >= off) ? buf[t - off] : 0;
        __syncthreads();
        buf[t] += v;
        __syncthreads();
    }
    if (t < NCLASS) base[t] = buf[t] - mine;   // inclusive -> exclusive
}

// ---------------------------------------------------------------------------
// K2c: offsets[c][b] = base[c] + exclusive_scan_b(cnt_t[c][:])  (block/class)
__global__ __launch_bounds__(NBLK)
void k2c_offsets(const int* __restrict__ cnt_t, const int* __restrict__ base,
                 int* __restrict__ offsets)
{
    __shared__ int buf[NBLK];
    const int c = blockIdx.x, t = threadIdx.x;
    const int v0 = cnt_t[c * NBLK + t];
    buf[t] = v0;
    __syncthreads();
    for (int off = 1; off < NBLK; off <<= 1) {
        const int v = (t >= off) ? buf[t - off] : 0;
        __syncthreads();
        buf[t] += v;
        __syncthreads();
    }
    offsets[c * NBLK + t] = base[c] + buf[t] - v0;
}

// ---------------------------------------------------------------------------
// K3: scatter row indices into class-sorted order
__global__ __launch_bounds__(K1_TPB)
void k3_scatter(const int* __restrict__ label, int n, int rpb,
                const int* __restrict__ offsets, int* __restrict__ sorted_idx)
{
    __shared__ int cursor[NCLASS];
    const int b = blockIdx.x, tid = threadIdx.x;
    for (int i = tid; i < NCLASS; i += K1_TPB)
        cursor[i] = offsets[i * NBLK + b];
    __syncthreads();
    const int r0 = b * rpb, r1 = min(n, r0 + rpb);
    for (int r = r0 + tid; r < r1; r += K1_TPB) {
        const int pos = atomicAdd(&cursor[label[r]], 1);
        sorted_idx[pos] = r;
    }
}

// ---------------------------------------------------------------------------
// K4: one block per class. Gather rows via sorted_idx, accumulate in
// registers (NO atomics), shuffle+LDS reduce, fused mean/EMA finalize.
// Thread layout: slot = tid>>4 (64 row slots), col = tid&15 (float4 column).
// A wave therefore reads 4 rows x 256 B contiguous each.
__global__ __launch_bounds__(K4_TPB)
void k4_reduce(const float* __restrict__ feat, const int* __restrict__ sorted_idx,
               const int* __restrict__ base, const int* __restrict__ totals,
               const float* __restrict__ proto, const int* __restrict__ step_ptr,
               float* __restrict__ out)
{
    __shared__ float red[16][D];
    const int c   = blockIdx.x;
    const int cnt = totals[c];
    const int st  = base[c];
    const int tid = threadIdx.x;
    const int slot = tid >> 4;
    const int col  = tid & 15;

    float4 acc = make_float4(0.f, 0.f, 0.f, 0.f);
    int j = slot;
    // 2-deep unroll for outstanding-load ILP
    for (; j + 64 < cnt; j += 128) {
        const int r0 = sorted_idx[st + j];
        const int r1 = sorted_idx[st + j + 64];
        const float4 v0 = *reinterpret_cast<const float4*>(feat + (size_t)r0 * D + col * 4);
        const float4 v1 = *reinterpret_cast<const float4*>(feat + (size_t)r1 * D + col * 4);
        acc.x += v0.x + v1.x; acc.y += v0.y + v1.y;
        acc.z += v0.z + v1.z; acc.w += v0.w + v1.w;
    }
    for (; j < cnt; j += 64) {
        const int r = sorted_idx[st + j];
        const float4 v = *reinterpret_cast<const float4*>(feat + (size_t)r * D + col * 4);
        acc.x += v.x; acc.y += v.y; acc.z += v.z; acc.w += v.w;
    }

    // reduce the 4 slots within each wave (slot differs in tid bits 4-5)
    #pragma unroll
    for (int m = 16; m <= 32; m <<= 1) {
        acc.x += __shfl_xor(acc.x, m);
        acc.y += __shfl_xor(acc.y, m);
        acc.z += __shfl_xor(acc.z, m);
        acc.w += __shfl_xor(acc.w, m);
    }
    const int wv = tid >> 6;                 // wave id 0..15
    if ((tid & 63) < 16) {                   // lanes 0..15 hold col sums
        red[wv][col * 4 + 0] = acc.x;
        red[wv][col * 4 + 1] = acc.y;
        red[wv][col * 4 + 2] = acc.z;
        red[wv][col * 4 + 3] = acc.w;
    }
    __syncthreads();

    if (tid < D) {
        float s = 0.f;
        #pragma unroll
        for (int k = 0; k < 16; ++k) s += red[k][tid];
        const float mean = s / (float)(cnt > 0 ? cnt : 1);
        const float p    = proto[c * D + tid];
        const unsigned long long nz = __ballot(p != 0.0f);
        const bool use_new = (nz == 0ULL) || (step_ptr[0] <= WARMUP);
        const float upd = use_new ? mean : (0.9f * p + 0.1f * mean);
        out[c * D + tid] = (cnt > 0) ? upd : p;
    }
}

// ---------------------------------------------------------------------------
extern "C" void kernel_launch(void* const* d_in, const int* in_sizes, int n_in,
                              void* d_out, int out_size, void* d_ws, size_t ws_size,
                              hipStream_t stream)
{
    const float* proto = (const float*)d_in[0];
    const float* feat  = (const float*)d_in[1];
    const int*   label = (const int*)d_in[2];
    const int*   step  = (const int*)d_in[3];
    float* out = (float*)d_out;
    const int n = in_sizes[2];

    char* ws = (char*)d_ws;
    int* cnt_t   = (int*)(ws);                        // NCLASS*NBLK ints (2.048 MB)
    int* offsets = (int*)(ws + 2048000);              // NCLASS*NBLK ints (2.048 MB)
    int* totals  = (int*)(ws + 4096000);              // 4 KB
    int* base    = (int*)(ws + 4100096);              // 4 KB
    int* sorted  = (int*)(ws + 4104192);              // n ints (8 MB)
    (void)ws_size;

    const int rpb = (n + NBLK - 1) / NBLK;

    k1_hist    <<<NBLK, K1_TPB, 0, stream>>>(label, n, rpb, cnt_t);
    k2a_totals <<<(NCLASS + 3) / 4, 256, 0, stream>>>(cnt_t, totals);
    k2b_scan   <<<1, 1024, 0, stream>>>(totals, base);
    k2c_offsets<<<NCLASS, NBLK, 0, stream>>>(cnt_t, base, offsets);
    k3_scatter <<<NBLK, K1_TPB, 0, stream>>>(label, n, rpb, offsets, sorted);
    k4_reduce  <<<NCLASS, K4_TPB, 0, stream>>>(feat, sorted, base, totals,
                                               proto, step, out);
}

// Round 4
// 130.519 us; speedup vs baseline: 5.1024x; 1.1418x over previous
//
#include <hip/hip_runtime.h>

#define NCLASS 1000
#define D 64
#define WARMUP 1000
#define NBLK 512            // partition blocks for histogram / scatter
#define K1_TPB 256
#define K3_TPB 1024
#define K4_TPB 1024

typedef float f32x4 __attribute__((ext_vector_type(4)));

// ---------------------------------------------------------------------------
// K1: per-block label histogram -> cnt_t[c * NBLK + b]   (transposed layout)
__global__ __launch_bounds__(K1_TPB)
void k1_hist(const int* __restrict__ label, int n, int rpb,
             int* __restrict__ cnt_t)
{
    __shared__ int hist[NCLASS];
    const int b = blockIdx.x, tid = threadIdx.x;
    for (int i = tid; i < NCLASS; i += K1_TPB) hist[i] = 0;
    __syncthreads();
    const int r0 = b * rpb, r1 = min(n, r0 + rpb);
    for (int r = r0 + tid; r < r1; r += K1_TPB)
        atomicAdd(&hist[label[r]], 1);
    __syncthreads();
    for (int i = tid; i < NCLASS; i += K1_TPB)
        cnt_t[i * NBLK + b] = hist[i];
}

// ---------------------------------------------------------------------------
// K2: per-class exclusive scan across blocks -> local_off[c][b]; the scan's
// last inclusive element IS the class total (k2a of the old chain, fused).
__global__ __launch_bounds__(NBLK)
void k2_offsets(const int* __restrict__ cnt_t,
                int* __restrict__ local_off, int* __restrict__ totals)
{
    __shared__ int buf[NBLK];
    const int c = blockIdx.x, t = threadIdx.x;
    const int v0 = cnt_t[c * NBLK + t];
    buf[t] = v0;
    __syncthreads();
    for (int off = 1; off < NBLK; off <<= 1) {
        const int v = (t >= off) ? buf[t - off] : 0;
        __syncthreads();
        buf[t] += v;
        __syncthreads();
    }
    local_off[c * NBLK + t] = buf[t] - v0;
    if (t == NBLK - 1) totals[c] = buf[t];
}

// ---------------------------------------------------------------------------
// K3: scatter row indices into class-sorted order. Each block re-derives the
// class base offsets (exclusive scan of the 1000 totals, 4 KB read) in LDS —
// this replaces the old standalone k2b kernel. Block 0 publishes base for k4.
__global__ __launch_bounds__(K3_TPB)
void k3_scatter(const int* __restrict__ label, int n, int rpb,
                const int* __restrict__ local_off, const int* __restrict__ totals,
                int* __restrict__ sorted_idx, int* __restrict__ base_out)
{
    __shared__ int cursor[NCLASS];
    __shared__ int buf[K3_TPB];
    const int b = blockIdx.x, tid = threadIdx.x;

    const int mine = (tid < NCLASS) ? totals[tid] : 0;
    buf[tid] = mine;
    __syncthreads();
    for (int off = 1; off < K3_TPB; off <<= 1) {
        const int v = (tid >= off) ? buf[tid - off] : 0;
        __syncthreads();
        buf[tid] += v;
        __syncthreads();
    }
    if (tid < NCLASS) {
        const int base = buf[tid] - mine;          // exclusive scan
        cursor[tid] = base + local_off[tid * NBLK + b];
        if (b == 0) base_out[tid] = base;
    }
    __syncthreads();

    const int r0 = b * rpb, r1 = min(n, r0 + rpb);
    for (int r = r0 + tid; r < r1; r += K3_TPB) {
        const int pos = atomicAdd(&cursor[label[r]], 1);
        sorted_idx[pos] = r;
    }
}

// ---------------------------------------------------------------------------
// K4: one block per class. Gather rows via sorted_idx, accumulate in
// registers (NO atomics), 4-deep unroll for outstanding-load ILP,
// non-temporal feature loads (read-once), shuffle+LDS reduce, fused EMA.
// Thread layout: slot = tid>>4 (64 row slots), col = tid&15 (float4 column).
__global__ __launch_bounds__(K4_TPB)
void k4_reduce(const float* __restrict__ feat, const int* __restrict__ sorted_idx,
               const int* __restrict__ base, const int* __restrict__ totals,
               const float* __restrict__ proto, const int* __restrict__ step_ptr,
               float* __restrict__ out)
{
    __shared__ float red[16][D];
    const int c   = blockIdx.x;
    const int cnt = totals[c];
    const int st  = base[c];
    const int tid = threadIdx.x;
    const int slot = tid >> 4;
    const int col  = tid & 15;

    f32x4 acc = {0.f, 0.f, 0.f, 0.f};
    int j = slot;
    for (; j + 192 < cnt; j += 256) {
        const int r0 = sorted_idx[st + j];
        const int r1 = sorted_idx[st + j + 64];
        const int r2 = sorted_idx[st + j + 128];
        const int r3 = sorted_idx[st + j + 192];
        const f32x4 v0 = __builtin_nontemporal_load((const f32x4*)(feat + (size_t)r0 * D + col * 4));
        const f32x4 v1 = __builtin_nontemporal_load((const f32x4*)(feat + (size_t)r1 * D + col * 4));
        const f32x4 v2 = __builtin_nontemporal_load((const f32x4*)(feat + (size_t)r2 * D + col * 4));
        const f32x4 v3 = __builtin_nontemporal_load((const f32x4*)(feat + (size_t)r3 * D + col * 4));
        acc += v0 + v1 + v2 + v3;
    }
    for (; j < cnt; j += 64) {
        const int r = sorted_idx[st + j];
        const f32x4 v = __builtin_nontemporal_load((const f32x4*)(feat + (size_t)r * D + col * 4));
        acc += v;
    }

    // reduce the 4 slots within each wave (slot differs in tid bits 4-5)
    #pragma unroll
    for (int m = 16; m <= 32; m <<= 1) {
        acc[0] += __shfl_xor(acc[0], m);
        acc[1] += __shfl_xor(acc[1], m);
        acc[2] += __shfl_xor(acc[2], m);
        acc[3] += __shfl_xor(acc[3], m);
    }
    const int wv = tid >> 6;                 // wave id 0..15
    if ((tid & 63) < 16) {                   // lanes 0..15 hold col sums
        red[wv][col * 4 + 0] = acc[0];
        red[wv][col * 4 + 1] = acc[1];
        red[wv][col * 4 + 2] = acc[2];
        red[wv][col * 4 + 3] = acc[3];
    }
    __syncthreads();

    if (tid < D) {
        float s = 0.f;
        #pragma unroll
        for (int k = 0; k < 16; ++k) s += red[k][tid];
        const float mean = s / (float)(cnt > 0 ? cnt : 1);
        const float p    = proto[c * D + tid];
        const unsigned long long nz = __ballot(p != 0.0f);
        const bool use_new = (nz == 0ULL) || (step_ptr[0] <= WARMUP);
        const float upd = use_new ? mean : (0.9f * p + 0.1f * mean);
        out[c * D + tid] = (cnt > 0) ? upd : p;
    }
}

// ---------------------------------------------------------------------------
extern "C" void kernel_launch(void* const* d_in, const int* in_sizes, int n_in,
                              void* d_out, int out_size, void* d_ws, size_t ws_size,
                              hipStream_t stream)
{
    const float* proto = (const float*)d_in[0];
    const float* feat  = (const float*)d_in[1];
    const int*   label = (const int*)d_in[2];
    const int*   step  = (const int*)d_in[3];
    float* out = (float*)d_out;
    const int n = in_sizes[2];

    char* ws = (char*)d_ws;
    int* cnt_t     = (int*)(ws);                  // NCLASS*NBLK ints (2.048 MB)
    int* local_off = (int*)(ws + 2048000);        // NCLASS*NBLK ints (2.048 MB)
    int* totals    = (int*)(ws + 4096000);        // 4 KB
    int* base      = (int*)(ws + 4100096);        // 4 KB
    int* sorted    = (int*)(ws + 4104192);        // n ints (8 MB)
    (void)ws_size;

    const int rpb  = (n + NBLK - 1) / NBLK;

    k1_hist   <<<NBLK, K1_TPB, 0, stream>>>(label, n, rpb, cnt_t);
    k2_offsets<<<NCLASS, NBLK, 0, stream>>>(cnt_t, local_off, totals);
    k3_scatter<<<NBLK, K3_TPB, 0, stream>>>(label, n, rpb, local_off, totals,
                                            sorted, base);
    k4_reduce <<<NCLASS, K4_TPB, 0, stream>>>(feat, sorted, base, totals,
                                              proto, step, out);
}

// Round 5
// 130.335 us; speedup vs baseline: 5.1097x; 1.0014x over previous
//
#include <hip/hip_runtime.h>

#define NCLASS 1000
#define D 64
#define WARMUP 1000
#define NBLK 256            // partition blocks for histogram / scatter
#define K1_TPB 512
#define K3_TPB 1024
#define K4_TPB 1024
#define UNR 8               // k4: outstanding row-loads per thread

typedef float f32x4 __attribute__((ext_vector_type(4)));

// ---------------------------------------------------------------------------
// K1: per-block label histogram -> cnt_t[c * NBLK + b]   (transposed layout)
__global__ __launch_bounds__(K1_TPB)
void k1_hist(const int* __restrict__ label, int n, int rpb,
             int* __restrict__ cnt_t)
{
    __shared__ int hist[NCLASS];
    const int b = blockIdx.x, tid = threadIdx.x;
    for (int i = tid; i < NCLASS; i += K1_TPB) hist[i] = 0;
    __syncthreads();
    const int r0 = b * rpb, r1 = min(n, r0 + rpb);
    for (int r = r0 + tid; r < r1; r += K1_TPB)
        atomicAdd(&hist[label[r]], 1);
    __syncthreads();
    for (int i = tid; i < NCLASS; i += K1_TPB)
        cnt_t[i * NBLK + b] = hist[i];
}

// ---------------------------------------------------------------------------
// K2: per-class exclusive scan across blocks -> local_off[c][b]; the scan's
// last inclusive element IS the class total.
__global__ __launch_bounds__(NBLK)
void k2_offsets(const int* __restrict__ cnt_t,
                int* __restrict__ local_off, int* __restrict__ totals)
{
    __shared__ int buf[NBLK];
    const int c = blockIdx.x, t = threadIdx.x;
    const int v0 = cnt_t[c * NBLK + t];
    buf[t] = v0;
    __syncthreads();
    for (int off = 1; off < NBLK; off <<= 1) {
        const int v = (t >= off) ? buf[t - off] : 0;
        __syncthreads();
        buf[t] += v;
        __syncthreads();
    }
    local_off[c * NBLK + t] = buf[t] - v0;
    if (t == NBLK - 1) totals[c] = buf[t];
}

// ---------------------------------------------------------------------------
// K3: scatter row indices into class-sorted order. Each block re-derives the
// class base offsets (exclusive scan of the 1000 totals) in LDS; block 0
// publishes base for k4.
__global__ __launch_bounds__(K3_TPB)
void k3_scatter(const int* __restrict__ label, int n, int rpb,
                const int* __restrict__ local_off, const int* __restrict__ totals,
                int* __restrict__ sorted_idx, int* __restrict__ base_out)
{
    __shared__ int cursor[NCLASS];
    __shared__ int buf[K3_TPB];
    const int b = blockIdx.x, tid = threadIdx.x;

    const int mine = (tid < NCLASS) ? totals[tid] : 0;
    buf[tid] = mine;
    __syncthreads();
    for (int off = 1; off < K3_TPB; off <<= 1) {
        const int v = (tid >= off) ? buf[tid - off] : 0;
        __syncthreads();
        buf[tid] += v;
        __syncthreads();
    }
    if (tid < NCLASS) {
        const int base = buf[tid] - mine;          // exclusive scan
        cursor[tid] = base + local_off[tid * NBLK + b];
        if (b == 0) base_out[tid] = base;
    }
    __syncthreads();

    const int r0 = b * rpb, r1 = min(n, r0 + rpb);
    for (int r = r0 + tid; r < r1; r += K3_TPB) {
        const int pos = atomicAdd(&cursor[label[r]], 1);
        sorted_idx[pos] = r;
    }
}

// ---------------------------------------------------------------------------
// K4: one block per class. Gather rows via sorted_idx, accumulate in
// registers (NO atomics), 8-deep unroll so each wave keeps 8 row-loads in
// flight (DRAM bank-level parallelism for the scattered 256B granules),
// non-temporal feature loads (read-once), shuffle+LDS reduce, fused EMA.
// Thread layout: slot = tid>>4 (64 row slots), col = tid&15 (float4 column).
__global__ __launch_bounds__(K4_TPB, 4)
void k4_reduce(const float* __restrict__ feat, const int* __restrict__ sorted_idx,
               const int* __restrict__ base, const int* __restrict__ totals,
               const float* __restrict__ proto, const int* __restrict__ step_ptr,
               float* __restrict__ out)
{
    __shared__ float red[16][D];
    const int c   = blockIdx.x;
    const int cnt = totals[c];
    const int st  = base[c];
    const int tid = threadIdx.x;
    const int slot = tid >> 4;
    const int col  = tid & 15;

    f32x4 acc0 = {0.f, 0.f, 0.f, 0.f};
    f32x4 acc1 = {0.f, 0.f, 0.f, 0.f};
    int j = slot;
    for (; j + (UNR - 1) * 64 < cnt; j += UNR * 64) {
        int rr[UNR];
        #pragma unroll
        for (int u = 0; u < UNR; ++u)
            rr[u] = sorted_idx[st + j + u * 64];
        f32x4 v[UNR];
        #pragma unroll
        for (int u = 0; u < UNR; ++u)
            v[u] = __builtin_nontemporal_load((const f32x4*)(feat + (size_t)rr[u] * D + col * 4));
        #pragma unroll
        for (int u = 0; u < UNR; u += 2) {
            acc0 += v[u];
            acc1 += v[u + 1];
        }
    }
    for (; j < cnt; j += 64) {
        const int r = sorted_idx[st + j];
        acc0 += __builtin_nontemporal_load((const f32x4*)(feat + (size_t)r * D + col * 4));
    }
    acc0 += acc1;

    // reduce the 4 slots within each wave (slot differs in tid bits 4-5)
    #pragma unroll
    for (int m = 16; m <= 32; m <<= 1) {
        acc0[0] += __shfl_xor(acc0[0], m);
        acc0[1] += __shfl_xor(acc0[1], m);
        acc0[2] += __shfl_xor(acc0[2], m);
        acc0[3] += __shfl_xor(acc0[3], m);
    }
    const int wv = tid >> 6;                 // wave id 0..15
    if ((tid & 63) < 16) {                   // lanes 0..15 hold col sums
        red[wv][col * 4 + 0] = acc0[0];
        red[wv][col * 4 + 1] = acc0[1];
        red[wv][col * 4 + 2] = acc0[2];
        red[wv][col * 4 + 3] = acc0[3];
    }
    __syncthreads();

    if (tid < D) {
        float s = 0.f;
        #pragma unroll
        for (int k = 0; k < 16; ++k) s += red[k][tid];
        const float mean = s / (float)(cnt > 0 ? cnt : 1);
        const float p    = proto[c * D + tid];
        const unsigned long long nz = __ballot(p != 0.0f);
        const bool use_new = (nz == 0ULL) || (step_ptr[0] <= WARMUP);
        const float upd = use_new ? mean : (0.9f * p + 0.1f * mean);
        out[c * D + tid] = (cnt > 0) ? upd : p;
    }
}

// ---------------------------------------------------------------------------
extern "C" void kernel_launch(void* const* d_in, const int* in_sizes, int n_in,
                              void* d_out, int out_size, void* d_ws, size_t ws_size,
                              hipStream_t stream)
{
    const float* proto = (const float*)d_in[0];
    const float* feat  = (const float*)d_in[1];
    const int*   label = (const int*)d_in[2];
    const int*   step  = (const int*)d_in[3];
    float* out = (float*)d_out;
    const int n = in_sizes[2];

    char* ws = (char*)d_ws;
    int* cnt_t     = (int*)(ws);                  // NCLASS*NBLK ints (1.024 MB)
    int* local_off = (int*)(ws + 1024000);        // NCLASS*NBLK ints (1.024 MB)
    int* totals    = (int*)(ws + 2048000);        // 4 KB
    int* base      = (int*)(ws + 2052096);        // 4 KB
    int* sorted    = (int*)(ws + 2056192);        // n ints (8 MB)
    (void)ws_size;

    const int rpb  = (n + NBLK - 1) / NBLK;

    k1_hist   <<<NBLK, K1_TPB, 0, stream>>>(label, n, rpb, cnt_t);
    k2_offsets<<<NCLASS, NBLK, 0, stream>>>(cnt_t, local_off, totals);
    k3_scatter<<<NBLK, K3_TPB, 0, stream>>>(label, n, rpb, local_off, totals,
                                            sorted, base);
    k4_reduce <<<NCLASS, K4_TPB, 0, stream>>>(feat, sorted, base, totals,
                                              proto, step, out);
}